// Round 3
// baseline (820.080 us; speedup 1.0000x reference)
//
#include <hip/hip_runtime.h>

// QuantizedLinear M=8192 K=4096 N=11008.
// Prepass: dequant int4-blockwise W -> f16 [N][K]; cvt x -> f16 [M][K].
// GEMM: 256x256 tile, BK=64, 512 thr (8 waves 2Mx4N), 4-phase/K-tile pipeline with
// 2-TILE prefetch distance (counted vmcnt(10), stage->wait gap = 5 phases ~800cyc >= HBM lat),
// XOR-swizzled LDS (linear gload_lds dest + pre-swizzled global src), setprio, XCD swizzle.

#define K_DIM 4096
#define N_DIM 11008
#define M_DIM 8192
#define NT_K 64  // K_DIM / 64

typedef _Float16 f16;
typedef _Float16 f16x8 __attribute__((ext_vector_type(8)));
typedef float f32x4 __attribute__((ext_vector_type(4)));

__device__ __forceinline__ void gload16(const void* g, void* lds) {
  __builtin_amdgcn_global_load_lds(
      (__attribute__((address_space(1))) void*)g,
      (__attribute__((address_space(3))) void*)lds,
      16, 0, 0);
}

__global__ __launch_bounds__(256) void cvt_x_kernel(const float* __restrict__ x,
                                                    f16* __restrict__ xo, int n8) {
  int i = blockIdx.x * blockDim.x + threadIdx.x;
  if (i >= n8) return;
  const float4* xv = (const float4*)x;
  float4 a = xv[2 * i];
  float4 b = xv[2 * i + 1];
  f16x8 o;
  o[0] = (f16)a.x; o[1] = (f16)a.y; o[2] = (f16)a.z; o[3] = (f16)a.w;
  o[4] = (f16)b.x; o[5] = (f16)b.y; o[6] = (f16)b.z; o[7] = (f16)b.w;
  *(f16x8*)(xo + (size_t)i * 8) = o;
}

__global__ __launch_bounds__(256) void dequant_kernel(const int* __restrict__ q,
                                                      const float* __restrict__ amax,
                                                      f16* __restrict__ wo, int n8) {
  int i = blockIdx.x * blockDim.x + threadIdx.x;
  if (i >= n8) return;
  const int4* qv = (const int4*)q;
  int4 a = qv[2 * i];
  int4 b = qv[2 * i + 1];
  float s = amax[i >> 3] * (1.0f / 7.0f);
  f16x8 o;
  o[0] = (f16)((float)a.x * s); o[1] = (f16)((float)a.y * s);
  o[2] = (f16)((float)a.z * s); o[3] = (f16)((float)a.w * s);
  o[4] = (f16)((float)b.x * s); o[5] = (f16)((float)b.y * s);
  o[6] = (f16)((float)b.z * s); o[7] = (f16)((float)b.w * s);
  *(f16x8*)(wo + (size_t)i * 8) = o;
}

// LDS map (bytes): A slot(parity p, khalf h) @ (p*2+h)*16384 ; B slot @ 65536 + (p*2+h)*16384.
// Each slot: K-half tile 256 rows x 32 f16 as [128 LDS rows][128 B], swizzle c' = c ^ ((r&7)<<4).
// Slot free times within tile t: B-lo after ph0, A-lo after ph1, B-hi after ph2, A-hi after ph3.
// Stage plan at tile t: ph0 -> A-hi[t+1] (slot pn,h1); ph1 -> B-lo[t+2] (slot p,h0);
//                       ph2 -> A-lo[t+2] (slot p,h0); ph3 -> B-hi[t+2] (slot p,h1).
// Waits: vmcnt(10) at ph1 (confirms B-hi[t],A-hi[t] for ph2/3) and ph3 (confirms
// B-lo[t+1],A-lo[t+1] for next ph0). Each confirmed stage was issued 5 phases earlier.
__global__ __launch_bounds__(512, 2) void gemm_f16_bt(const f16* __restrict__ A,
                                                      const f16* __restrict__ B,
                                                      const float* __restrict__ bias,
                                                      float* __restrict__ C) {
  __shared__ __align__(16) char lds[131072];

  const int tid = threadIdx.x;
  const int w = tid >> 6;
  const int l = tid & 63;
  const int wr = w >> 2;  // 0..1
  const int wc = w & 3;   // 0..3

  // bijective XCD swizzle: nwg = 1376 = 8 * 172
  const int wg = blockIdx.x;
  const int swz = (wg & 7) * 172 + (wg >> 3);
  const int mt = swz / 43;
  const int nt = swz % 43;
  const int m0 = mt * 256;
  const int n0 = nt * 256;

  const int lr = l & 15;
  const int g = l >> 4;
  const int laneoff = ((lr >> 1) << 7) | (((((lr & 1) << 6) | (g << 4))) ^ (((lr >> 1) & 7) << 4));

  // pre-swizzled staging sources: instr j covers unit chunk (j*8+w)*1024 + l*16
  const char* Asrc[2];
  const char* Bsrc[2];
#pragma unroll
  for (int j = 0; j < 2; ++j) {
    const int u = ((j * 8 + w) << 10) + l * 16;
    const int r = u >> 7;
    const int cp = (u & 127) ^ ((r & 7) << 4);
    const int ra = 2 * r + (cp >> 6);
    const int kb = cp & 63;
    Asrc[j] = (const char*)A + (size_t)(m0 + ra) * (K_DIM * 2) + kb;
    Bsrc[j] = (const char*)B + (size_t)(n0 + ra) * (K_DIM * 2) + kb;
  }

  char* ldsc = (char*)lds;

#define STAGE_A(dst_off, koff)                              \
  {                                                         \
    char* d_ = ldsc + (dst_off) + w * 1024;                 \
    gload16(Asrc[0] + (koff), d_);                          \
    gload16(Asrc[1] + (koff), d_ + 8192);                   \
  }
#define STAGE_B(dst_off, koff)                              \
  {                                                         \
    char* d_ = ldsc + (dst_off) + w * 1024;                 \
    gload16(Bsrc[0] + (koff), d_);                          \
    gload16(Bsrc[1] + (koff), d_ + 8192);                   \
  }

  f32x4 acc[8][4];
#pragma unroll
  for (int i = 0; i < 8; ++i)
#pragma unroll
    for (int j = 0; j < 4; ++j) acc[i][j] = (f32x4){0.f, 0.f, 0.f, 0.f};

  // prologue (steady-state issue order): Blo0,Alo0,Bhi0,Ahi0,Blo1,Alo1,Bhi1 = 14 loads
  STAGE_B(65536, 0);
  STAGE_A(0, 0);
  STAGE_B(65536 + 16384, 64);
  STAGE_A(16384, 64);
  STAGE_B(65536 + 32768, 128);
  STAGE_A(32768, 128);
  STAGE_B(65536 + 32768 + 16384, 192);
  asm volatile("s_waitcnt vmcnt(10)" ::: "memory");  // confirms Blo0, Alo0
  __builtin_amdgcn_s_barrier();

  for (int t = 0; t < NT_K; ++t) {
    const int p = t & 1;
    const int pn = p ^ 1;
    const int Ab = p * 32768;
    const int Bb = 65536 + p * 32768;
    const int t1 = (t + 1 < NT_K) ? (t + 1) : (NT_K - 1);
    const int t2 = (t + 2 < NT_K) ? (t + 2) : (NT_K - 1);
    const int k1 = t1 * 128;
    const int k2 = t2 * 128;

    f16x8 bf[4];
    f16x8 af[4];
#pragma unroll
    for (int pi = 0; pi < 4; ++pi) {
      const int kk = pi >> 1;
      const int mh = pi & 1;

      if (mh == 0) {
#pragma unroll
        for (int ni = 0; ni < 4; ++ni)
          bf[ni] = *(const f16x8*)(ldsc + Bb + kk * 16384 + ((wc * 64 + ni * 16) << 6) + laneoff);
      }
#pragma unroll
      for (int mi = 0; mi < 4; ++mi)
        af[mi] = *(const f16x8*)(ldsc + Ab + kk * 16384 +
                                 ((wr * 128 + mh * 64 + mi * 16) << 6) + laneoff);

      if (pi == 0) {
        STAGE_A(pn * 32768 + 16384, k1 + 64);        // A-hi[t+1]
      } else if (pi == 1) {
        STAGE_B(65536 + p * 32768, k2);              // B-lo[t+2]
      } else if (pi == 2) {
        STAGE_A(p * 32768, k2);                      // A-lo[t+2]
      } else {
        STAGE_B(65536 + p * 32768 + 16384, k2 + 64); // B-hi[t+2]
      }

      __builtin_amdgcn_s_barrier();
      __builtin_amdgcn_s_setprio(1);
#pragma unroll
      for (int mi = 0; mi < 4; ++mi)
#pragma unroll
        for (int ni = 0; ni < 4; ++ni)
          acc[mh * 4 + mi][ni] = __builtin_amdgcn_mfma_f32_16x16x32_f16(
              af[mi], bf[ni], acc[mh * 4 + mi][ni], 0, 0, 0);
      __builtin_amdgcn_s_setprio(0);
      if (mh == 1) asm volatile("s_waitcnt vmcnt(10)" ::: "memory");
      __builtin_amdgcn_s_barrier();
    }
  }

  // epilogue: C/D layout col = lane&15, row = (lane>>4)*4 + j
  const int orow = g * 4;
  float bv[4];
#pragma unroll
  for (int ni = 0; ni < 4; ++ni) bv[ni] = bias[n0 + wc * 64 + ni * 16 + lr];
#pragma unroll
  for (int mi = 0; mi < 8; ++mi) {
    const int row = m0 + wr * 128 + mi * 16 + orow;
#pragma unroll
    for (int ni = 0; ni < 4; ++ni) {
      const size_t cb = (size_t)row * N_DIM + (n0 + wc * 64 + ni * 16 + lr);
#pragma unroll
      for (int j = 0; j < 4; ++j) C[cb + (size_t)j * N_DIM] = acc[mi][ni][j] + bv[ni];
    }
  }
#undef STAGE_A
#undef STAGE_B
}

extern "C" void kernel_launch(void* const* d_in, const int* in_sizes, int n_in,
                              void* d_out, int out_size, void* d_ws, size_t ws_size,
                              hipStream_t stream) {
  const float* x = (const float*)d_in[0];
  const int* wq = (const int*)d_in[1];
  const float* amax = (const float*)d_in[2];
  const float* bias = (const float*)d_in[3];
  float* out = (float*)d_out;

  f16* Xh = (f16*)d_ws;                                       // 64 MB
  f16* Wh = (f16*)((char*)d_ws + (size_t)M_DIM * K_DIM * 2);  // 90 MB

  {
    int n8 = M_DIM * K_DIM / 8;
    cvt_x_kernel<<<n8 / 256, 256, 0, stream>>>(x, Xh, n8);
  }
  {
    int n8 = N_DIM * K_DIM / 8;
    dequant_kernel<<<n8 / 256, 256, 0, stream>>>(wq, amax, Wh, n8);
  }
  {
    dim3 grid((M_DIM / 256) * (N_DIM / 256));  // 32*43 = 1376
    gemm_f16_bt<<<grid, 512, 0, stream>>>(Xh, Wh, bias, out);
  }
}

// Round 5
// 769.190 us; speedup vs baseline: 1.0662x; 1.0662x over previous
//
#include <hip/hip_runtime.h>

// QuantizedLinear M=8192 K=4096 N=11008.
// Prepass (fused): dequant int4-blockwise W -> f16 [N][K]; cvt x -> f16 [M][K] (nt loads).
// GEMM: 256x256 tile, BK=64, 512 thr (8 waves 2Mx4N), 4-phase/K-tile pipeline,
// A triple-parity ring (96KB) + B double-parity (64KB) = 160KB LDS, ONE vmcnt(8)/tile,
// XOR-swizzled LDS (linear gload_lds dest + pre-swizzled global src), setprio, XCD swizzle,
// nontemporal f32 C stores (keep A/B resident in LLC).

#define K_DIM 4096
#define N_DIM 11008
#define M_DIM 8192
#define NT_K 64     // K_DIM / 64
#define AB_OFF 98304  // A region [0,98304): 3 parities x 32KB; B region: 2 parities x 32KB

typedef _Float16 f16;
typedef _Float16 f16x8 __attribute__((ext_vector_type(8)));
typedef float f32x4 __attribute__((ext_vector_type(4)));
typedef float fv4 __attribute__((ext_vector_type(4)));
typedef int iv4 __attribute__((ext_vector_type(4)));

__device__ __forceinline__ void gload16(const void* g, void* lds) {
  __builtin_amdgcn_global_load_lds(
      (__attribute__((address_space(1))) void*)g,
      (__attribute__((address_space(3))) void*)lds,
      16, 0, 0);
}

// fused prepass: threads [0,n8x) convert x (f32->f16, 8/thread); rest dequant W (8/thread).
__global__ __launch_bounds__(256) void prep_kernel(const float* __restrict__ x,
                                                   f16* __restrict__ xo, int n8x,
                                                   const int* __restrict__ q,
                                                   const float* __restrict__ amax,
                                                   f16* __restrict__ wo, int n8w) {
  int i = blockIdx.x * blockDim.x + threadIdx.x;
  if (i < n8x) {
    const fv4* xv = (const fv4*)x;
    fv4 a = __builtin_nontemporal_load(xv + 2 * (size_t)i);
    fv4 b = __builtin_nontemporal_load(xv + 2 * (size_t)i + 1);
    f16x8 o;
    o[0] = (f16)a.x; o[1] = (f16)a.y; o[2] = (f16)a.z; o[3] = (f16)a.w;
    o[4] = (f16)b.x; o[5] = (f16)b.y; o[6] = (f16)b.z; o[7] = (f16)b.w;
    *(f16x8*)(xo + (size_t)i * 8) = o;
  } else {
    int j = i - n8x;
    if (j >= n8w) return;
    const iv4* qv = (const iv4*)q;
    iv4 a = __builtin_nontemporal_load(qv + 2 * (size_t)j);
    iv4 b = __builtin_nontemporal_load(qv + 2 * (size_t)j + 1);
    float s = amax[j >> 3] * (1.0f / 7.0f);
    f16x8 o;
    o[0] = (f16)((float)a.x * s); o[1] = (f16)((float)a.y * s);
    o[2] = (f16)((float)a.z * s); o[3] = (f16)((float)a.w * s);
    o[4] = (f16)((float)b.x * s); o[5] = (f16)((float)b.y * s);
    o[6] = (f16)((float)b.z * s); o[7] = (f16)((float)b.w * s);
    *(f16x8*)(wo + (size_t)j * 8) = o;
  }
}

// LDS half-slots of 16KB: A(parity ap/32768, khalf h) @ ap + h*16384 (ap in {0,32768,65536});
// B(parity p, khalf h) @ AB_OFF + p*32768 + h*16384.
// Each half-slot: K-half tile 256 rows x 32 f16 as [128 LDS rows][128 B], swizzle c'=c^((r&7)<<4).
// Stage plan tile t: ph0 -> Alo[t+2]; ph1 -> Ahi[t+2]; ph2 -> Blo[t+2]; ph3 -> Bhi[t+2];
// single vmcnt(8) at ph3 confirms the 4 half-slots of tile t+1 (issued during t-1).
__global__ __launch_bounds__(512, 2) void gemm_f16_bt(const f16* __restrict__ A,
                                                      const f16* __restrict__ B,
                                                      const float* __restrict__ bias,
                                                      float* __restrict__ C) {
  __shared__ __align__(16) char lds[163840];

  const int tid = threadIdx.x;
  const int w = tid >> 6;
  const int l = tid & 63;
  const int wr = w >> 2;  // 0..1
  const int wc = w & 3;   // 0..3

  // bijective XCD swizzle: nwg = 1376 = 8 * 172
  const int wg = blockIdx.x;
  const int swz = (wg & 7) * 172 + (wg >> 3);
  const int mt = swz / 43;
  const int nt = swz % 43;
  const int m0 = mt * 256;
  const int n0 = nt * 256;

  const int lr = l & 15;
  const int g = l >> 4;
  const int laneoff = ((lr >> 1) << 7) | (((((lr & 1) << 6) | (g << 4))) ^ (((lr >> 1) & 7) << 4));

  // pre-swizzled staging sources: instr j covers unit chunk (j*8+w)*1024 + l*16
  const char* Asrc[2];
  const char* Bsrc[2];
#pragma unroll
  for (int j = 0; j < 2; ++j) {
    const int u = ((j * 8 + w) << 10) + l * 16;
    const int r = u >> 7;
    const int cp = (u & 127) ^ ((r & 7) << 4);
    const int ra = 2 * r + (cp >> 6);
    const int kb = cp & 63;
    Asrc[j] = (const char*)A + (size_t)(m0 + ra) * (K_DIM * 2) + kb;
    Bsrc[j] = (const char*)B + (size_t)(n0 + ra) * (K_DIM * 2) + kb;
  }

  char* ldsc = (char*)lds;

#define STAGE_A(dst_off, koff)              \
  {                                         \
    char* d_ = ldsc + (dst_off) + w * 1024; \
    gload16(Asrc[0] + (koff), d_);          \
    gload16(Asrc[1] + (koff), d_ + 8192);   \
  }
#define STAGE_B(dst_off, koff)              \
  {                                         \
    char* d_ = ldsc + (dst_off) + w * 1024; \
    gload16(Bsrc[0] + (koff), d_);          \
    gload16(Bsrc[1] + (koff), d_ + 8192);   \
  }

  f32x4 acc[8][4];
#pragma unroll
  for (int i = 0; i < 8; ++i)
#pragma unroll
    for (int j = 0; j < 4; ++j) acc[i][j] = (f32x4){0.f, 0.f, 0.f, 0.f};

  // prologue: tiles 0 and 1, steady-state order {Alo,Ahi,Blo,Bhi} = 16 loads
  STAGE_A(0, 0);
  STAGE_A(16384, 64);
  STAGE_B(AB_OFF, 0);
  STAGE_B(AB_OFF + 16384, 64);
  STAGE_A(32768, 128);
  STAGE_A(32768 + 16384, 192);
  STAGE_B(AB_OFF + 32768, 128);
  STAGE_B(AB_OFF + 32768 + 16384, 192);
  asm volatile("s_waitcnt vmcnt(8)" ::: "memory");  // tile 0 fully landed
  __builtin_amdgcn_s_barrier();

  int ap = 0;       // A parity base of tile t
  int ap2 = 65536;  // A parity base of tile t+2

  for (int t = 0; t < NT_K; ++t) {
    const int p = t & 1;
    const int Bb = AB_OFF + p * 32768;
    const int t2 = (t + 2 < NT_K) ? (t + 2) : (NT_K - 1);
    const int k2 = t2 * 128;  // byte k-offset of tile staged 2 ahead

    f16x8 bf[4];
    f16x8 af[4];
#pragma unroll
    for (int pi = 0; pi < 4; ++pi) {
      const int kk = pi >> 1;
      const int mh = pi & 1;

      if (mh == 0) {
#pragma unroll
        for (int ni = 0; ni < 4; ++ni)
          bf[ni] = *(const f16x8*)(ldsc + Bb + kk * 16384 + ((wc * 64 + ni * 16) << 6) + laneoff);
      }
#pragma unroll
      for (int mi = 0; mi < 4; ++mi)
        af[mi] = *(const f16x8*)(ldsc + ap + kk * 16384 +
                                 ((wr * 128 + mh * 64 + mi * 16) << 6) + laneoff);

      if (pi == 0) {
        STAGE_A(ap2, k2);                 // A-lo[t+2]
      } else if (pi == 1) {
        STAGE_A(ap2 + 16384, k2 + 64);    // A-hi[t+2]
      } else if (pi == 2) {
        STAGE_B(Bb, k2);                  // B-lo[t+2] (same parity as t)
      } else {
        STAGE_B(Bb + 16384, k2 + 64);     // B-hi[t+2]
      }

      __builtin_amdgcn_s_barrier();
      __builtin_amdgcn_s_setprio(1);
#pragma unroll
      for (int mi = 0; mi < 4; ++mi)
#pragma unroll
        for (int ni = 0; ni < 4; ++ni)
          acc[mh * 4 + mi][ni] = __builtin_amdgcn_mfma_f32_16x16x32_f16(
              af[mi], bf[ni], acc[mh * 4 + mi][ni], 0, 0, 0);
      __builtin_amdgcn_s_setprio(0);
      if (pi == 3) asm volatile("s_waitcnt vmcnt(8)" ::: "memory");
      __builtin_amdgcn_s_barrier();
    }

    ap += 32768;  if (ap == AB_OFF) ap = 0;
    ap2 += 32768; if (ap2 == AB_OFF) ap2 = 0;
  }

  // epilogue: C/D layout col = lane&15, row = (lane>>4)*4 + j ; nontemporal stores
  const int orow = g * 4;
  float bv[4];
#pragma unroll
  for (int ni = 0; ni < 4; ++ni) bv[ni] = bias[n0 + wc * 64 + ni * 16 + lr];
#pragma unroll
  for (int mi = 0; mi < 8; ++mi) {
    const int row = m0 + wr * 128 + mi * 16 + orow;
#pragma unroll
    for (int ni = 0; ni < 4; ++ni) {
      const size_t cb = (size_t)row * N_DIM + (n0 + wc * 64 + ni * 16 + lr);
#pragma unroll
      for (int j = 0; j < 4; ++j)
        __builtin_nontemporal_store(acc[mi][ni][j] + bv[ni], &C[cb + (size_t)j * N_DIM]);
    }
  }
#undef STAGE_A
#undef STAGE_B
}

extern "C" void kernel_launch(void* const* d_in, const int* in_sizes, int n_in,
                              void* d_out, int out_size, void* d_ws, size_t ws_size,
                              hipStream_t stream) {
  const float* x = (const float*)d_in[0];
  const int* wq = (const int*)d_in[1];
  const float* amax = (const float*)d_in[2];
  const float* bias = (const float*)d_in[3];
  float* out = (float*)d_out;

  f16* Xh = (f16*)d_ws;                                       // 64 MB
  f16* Wh = (f16*)((char*)d_ws + (size_t)M_DIM * K_DIM * 2);  // 90 MB

  {
    int n8x = M_DIM * K_DIM / 8;  // 4194304 (multiple of 256 -> no mixed block)
    int n8w = N_DIM * K_DIM / 8;  // 5636096
    int nthr = n8x + n8w;
    prep_kernel<<<(nthr + 255) / 256, 256, 0, stream>>>(x, Xh, n8x, wq, amax, Wh, n8w);
  }
  {
    dim3 grid((M_DIM / 256) * (N_DIM / 256));  // 32*43 = 1376
    gemm_f16_bt<<<grid, 512, 0, stream>>>(Xh, Wh, bias, out);
  }
}